// Round 5
// baseline (198.406 us; speedup 1.0000x reference)
//
#include <hip/hip_runtime.h>

// Gaussian mixture field evaluation via MFMA:
//   out[m] = sum_n exp2( K*q[m,n] + log2(I_n) ),  K = -0.5*log2(e)
// q expressed as dot(P[m][0..9], C[n][0..9]) with split-f16 (hi/lo) operands:
// products hi*hi + lo*hi + hi*lo -> 30 K-slots -> one mfma_f32_16x16x32_f16
// per 16x16 q-tile. Round 5: 4 point-tiles per wave so each LDS B-frag read
// feeds 4 MFMAs (LDS pipe was ~15-20 us of the round-4 56 us).
//
// Verified gfx950 layouts (learn_hip m89/m91):
//   A-frag: lane holds A[m=lane&15][k=(lane>>4)*8+j], j=0..7
//   B-frag: lane holds B[k=(lane>>4)*8+j][n=lane&15]
//   D:      lane holds D[row=(lane>>4)*4+r][col=lane&15], r=0..3

#define M_POINTS 65536
#define N_GAUSS  4096
#define KNEG     (-0.72134752044448170f)   // -0.5 * log2(e)

typedef _Float16 half8   __attribute__((ext_vector_type(8)));
typedef float    float4v __attribute__((ext_vector_type(4)));

__device__ __forceinline__ float fast_exp2(float x) {
#if defined(__has_builtin)
#if __has_builtin(__builtin_amdgcn_exp2f)
    return __builtin_amdgcn_exp2f(x);   // raw v_exp_f32
#else
    return exp2f(x);
#endif
#else
    return exp2f(x);
#endif
}

// ---------------------------------------------------------------------------
// Kernel 1: per-gaussian coefficient precompute in MFMA B-operand fragment
// layout (bfrag[tile*64 + lane] = half8), plus d_out zeroing (atomic partials
// in kernel 2 need zeroed output; fusing drops a memset node).
// ---------------------------------------------------------------------------
__global__ __launch_bounds__(256) void precompute_bfrag(
    const float* __restrict__ pos, const float* __restrict__ scl,
    const float* __restrict__ rot, const float* __restrict__ inten,
    half8* __restrict__ bfrag, float4* __restrict__ out_zero)
{
    int n = blockIdx.x * 256 + threadIdx.x;
    if (n >= N_GAUSS) return;

    // zero d_out: 65536 floats = 16384 float4 across 4096 threads
    {
        float4 z = make_float4(0.f, 0.f, 0.f, 0.f);
        out_zero[n]         = z;
        out_zero[n + 4096]  = z;
        out_zero[n + 8192]  = z;
        out_zero[n + 12288] = z;
    }

    float qw = rot[4*n+0], qx = rot[4*n+1], qy = rot[4*n+2], qz = rot[4*n+3];
    float nrm = sqrtf(qw*qw + qx*qx + qy*qy + qz*qz) + 1e-8f;
    float ir = 1.0f / nrm;
    qw *= ir; qx *= ir; qy *= ir; qz *= ir;

    float r00 = 1.f - 2.f*(qy*qy + qz*qz);
    float r01 = 2.f*(qx*qy - qz*qw);
    float r02 = 2.f*(qx*qz + qy*qw);
    float r10 = 2.f*(qx*qy + qz*qw);
    float r11 = 1.f - 2.f*(qx*qx + qz*qz);
    float r12 = 2.f*(qy*qz - qx*qw);
    float r20 = 2.f*(qx*qz - qy*qw);
    float r21 = 2.f*(qy*qz + qx*qw);
    float r22 = 1.f - 2.f*(qx*qx + qy*qy);

    float s0 = fabsf(scl[3*n+0]) + 1e-6f;
    float s1 = fabsf(scl[3*n+1]) + 1e-6f;
    float s2 = fabsf(scl[3*n+2]) + 1e-6f;
    float w0 = 1.f/(s0*s0), w1 = 1.f/(s1*s1), w2 = 1.f/(s2*s2);

    float a00 = r00*r00*w0 + r01*r01*w1 + r02*r02*w2;
    float a01 = r00*r10*w0 + r01*r11*w1 + r02*r12*w2;
    float a02 = r00*r20*w0 + r01*r21*w1 + r02*r22*w2;
    float a11 = r10*r10*w0 + r11*r11*w1 + r12*r12*w2;
    float a12 = r10*r20*w0 + r11*r21*w1 + r12*r22*w2;
    float a22 = r20*r20*w0 + r21*r21*w1 + r22*r22*w2;

    float p0 = pos[3*n+0], p1 = pos[3*n+1], p2 = pos[3*n+2];
    float b0 = a00*p0 + a01*p1 + a02*p2;
    float b1 = a01*p0 + a11*p1 + a12*p2;
    float b2 = a02*p0 + a12*p1 + a22*p2;
    float c  = b0*p0 + b1*p1 + b2*p2;

    float I = fmaxf(inten[n], 1e-30f);   // I=0 -> t very negative -> exp2 -> 0

    float C[10];
    C[0] = KNEG * a00;       C[1] = KNEG * a11;       C[2] = KNEG * a22;
    C[3] = 2.f*KNEG * a01;   C[4] = 2.f*KNEG * a02;   C[5] = 2.f*KNEG * a12;
    C[6] = -2.f*KNEG * b0;   C[7] = -2.f*KNEG * b1;   C[8] = -2.f*KNEG * b2;
    C[9] = KNEG * c + log2f(I);

    _Float16 chi[10], clo[10];
#pragma unroll
    for (int j = 0; j < 10; ++j) {
        chi[j] = (_Float16)C[j];
        clo[j] = (_Float16)(C[j] - (float)chi[j]);
    }

    const int tile = n >> 4, nl = n & 15;
#pragma unroll
    for (int q = 0; q < 4; ++q) {
        half8 v;
#pragma unroll
        for (int j = 0; j < 8; ++j) {
            const int k = q*8 + j;
            _Float16 h = (_Float16)0.f;
            if (k < 30) {
                const int jm = k / 3, s = k % 3;
                h = (s == 2) ? clo[jm] : chi[jm];
            }
            v[j] = h;
        }
        bfrag[tile*64 + q*16 + nl] = v;
    }
}

// ---------------------------------------------------------------------------
// Kernel 2: main evaluation. grid(256, 4) x 256 threads (4 waves/block,
// 4 blocks/CU; LDS 32 KiB x 4 = 128 KiB of 160). Each wave owns FOUR
// 16-point tiles (4 A-frags, 16 VGPRs, built once) -> one ds_read_b128 of a
// B-frag feeds 4 MFMAs and 16 independent exp2s. blockIdx.y splits the 256
// gaussian tiles into 4 chunks of 64 (4 rounds of 16 LDS-staged tiles,
// double-buffered). Partials combined with atomicAdd (4 per output).
// ---------------------------------------------------------------------------
#define PT_SLABS  256      // 65536 / 256 points per block
#define G_SPLIT   4
#define G_TILES   (256 / G_SPLIT)   // 64 tiles per block
#define RT        16                // tiles per LDS round
#define ROUNDS    (G_TILES / RT)    // 4

__global__ __launch_bounds__(256, 4) void gauss_eval(
    const float* __restrict__ pts,
    const half8* __restrict__ bfrag,
    float* __restrict__ out)
{
    __shared__ half8 lds[2 * RT * 64];   // 2 bufs x 16 tiles x 1 KiB = 32 KiB

    const int tid  = threadIdx.x;
    const int lane = tid & 63;
    const int wv   = tid >> 6;
    const int ml   = lane & 15;          // A m-index / B n-index / D col
    const int q    = lane >> 4;          // k-group / D row-group

    // ---- build 4 A-frags for this wave's 64 points (one-time) ----
    const int base = blockIdx.x * 256 + wv * 64;   // first of 64 points
    half8 af[4];
#pragma unroll
    for (int f = 0; f < 4; ++f) {
        const int pt = base + f*16 + ml;
        const float x = pts[3*pt+0], y = pts[3*pt+1], z = pts[3*pt+2];
        const float P[10] = {x*x, y*y, z*z, x*y, x*z, y*z, x, y, z, 1.f};
        _Float16 v[32];
#pragma unroll
        for (int j = 0; j < 10; ++j) {
            _Float16 hi = (_Float16)P[j];
            _Float16 lo = (_Float16)(P[j] - (float)hi);
            v[3*j]   = hi;   // pairs with chi
            v[3*j+1] = lo;   // pairs with chi
            v[3*j+2] = hi;   // pairs with clo
        }
        v[30] = (_Float16)0.f; v[31] = (_Float16)0.f;
#pragma unroll
        for (int j = 0; j < 8; ++j) {
            _Float16 lo01 = (q & 1) ? v[8 + j]  : v[j];
            _Float16 hi23 = (q & 1) ? v[24 + j] : v[16 + j];
            af[f][j] = (q & 2) ? hi23 : lo01;
        }
    }

    float acc[4][4];
#pragma unroll
    for (int f = 0; f < 4; ++f)
#pragma unroll
        for (int r = 0; r < 4; ++r) acc[f][r] = 0.f;
    const float4v zero4 = {0.f, 0.f, 0.f, 0.f};

    const int gtile0 = blockIdx.y * G_TILES;

    // ---- stage round 0 (each wave: 4 tiles, 16 B/lane coalesced) ----
    {
        const half8* src = bfrag + (gtile0 + wv*4) * 64;
        half8* dst = lds + (wv*4) * 64;
#pragma unroll
        for (int i = 0; i < 4; ++i) dst[i*64 + lane] = src[i*64 + lane];
    }
    __syncthreads();

    for (int r = 0; r < ROUNDS; ++r) {
        const half8* cur = lds + (r & 1) * (RT*64);
        half8* nxt       = lds + ((r + 1) & 1) * (RT*64);

        if (r < ROUNDS - 1) {   // prefetch next round into the other buffer
            const half8* src = bfrag + (gtile0 + (r+1)*RT + wv*4) * 64;
            half8* dst = nxt + (wv*4) * 64;
#pragma unroll
            for (int i = 0; i < 4; ++i) dst[i*64 + lane] = src[i*64 + lane];
        }

#pragma unroll
        for (int i = 0; i < RT; ++i) {
            half8 b = cur[i*64 + lane];
            float4v d0 = __builtin_amdgcn_mfma_f32_16x16x32_f16(af[0], b, zero4, 0, 0, 0);
            float4v d1 = __builtin_amdgcn_mfma_f32_16x16x32_f16(af[1], b, zero4, 0, 0, 0);
            float4v d2 = __builtin_amdgcn_mfma_f32_16x16x32_f16(af[2], b, zero4, 0, 0, 0);
            float4v d3 = __builtin_amdgcn_mfma_f32_16x16x32_f16(af[3], b, zero4, 0, 0, 0);
#pragma unroll
            for (int r4 = 0; r4 < 4; ++r4) {
                acc[0][r4] += fast_exp2(d0[r4]);
                acc[1][r4] += fast_exp2(d1[r4]);
                acc[2][r4] += fast_exp2(d2[r4]);
                acc[3][r4] += fast_exp2(d3[r4]);
            }
        }
        __syncthreads();
    }

    // ---- reduce over the 16 gaussian lanes within each quad ----
#pragma unroll
    for (int m = 1; m <= 8; m <<= 1) {
#pragma unroll
        for (int f = 0; f < 4; ++f) {
#pragma unroll
            for (int r = 0; r < 4; ++r)
                acc[f][r] += __shfl_xor(acc[f][r], m);
        }
    }

    // lane ml==0 of quad q holds sums for points base + f*16 + q*4 + r
    if (ml == 0) {
#pragma unroll
        for (int f = 0; f < 4; ++f) {
#pragma unroll
            for (int r = 0; r < 4; ++r)
                atomicAdd(&out[base + f*16 + q*4 + r], acc[f][r]);
        }
    }
}

extern "C" void kernel_launch(void* const* d_in, const int* in_sizes, int n_in,
                              void* d_out, int out_size, void* d_ws, size_t ws_size,
                              hipStream_t stream) {
    const float* sample_points = (const float*)d_in[0];
    const float* positions     = (const float*)d_in[1];
    const float* scales        = (const float*)d_in[2];
    const float* rotations     = (const float*)d_in[3];
    const float* intensities   = (const float*)d_in[4];

    half8* bfrag = (half8*)d_ws;   // 256 KiB

    precompute_bfrag<<<N_GAUSS / 256, 256, 0, stream>>>(
        positions, scales, rotations, intensities, bfrag, (float4*)d_out);

    gauss_eval<<<dim3(PT_SLABS, G_SPLIT), 256, 0, stream>>>(
        sample_points, bfrag, (float*)d_out);
}

// Round 6
// 170.631 us; speedup vs baseline: 1.1628x; 1.1628x over previous
//
#include <hip/hip_runtime.h>

// Gaussian mixture field evaluation via MFMA:
//   out[m] = sum_n exp2( K*q[m,n] + log2(I_n) ),  K = -0.5*log2(e)
// q expressed as dot(P[m][0..9], C[n][0..9]) with split-f16 (hi/lo) operands:
// products hi*hi + lo*hi + hi*lo -> 30 K-slots -> one mfma_f32_16x16x32_f16
// per 16x16 q-tile. 4 point-tiles per wave: each LDS B-frag read feeds 4
// MFMAs / 16 exp2s.
//
// Round 6: round-5 dataflow, but NO local arrays in the eval kernel —
// round 5's acc[4][4]/v[32] arrays failed SROA and went to scratch
// (FETCH 182 MB / WRITE 364 MB of spill traffic, 2.5x regression).
// Everything is named scalars / first-class vector values now.
//
// Verified gfx950 layouts (learn_hip m89/m91):
//   A-frag: lane holds A[m=lane&15][k=(lane>>4)*8+j], j=0..7
//   B-frag: lane holds B[k=(lane>>4)*8+j][n=lane&15]
//   D:      lane holds D[row=(lane>>4)*4+r][col=lane&15], r=0..3

#define M_POINTS 65536
#define N_GAUSS  4096
#define KNEG     (-0.72134752044448170f)   // -0.5 * log2(e)

typedef _Float16 half8   __attribute__((ext_vector_type(8)));
typedef float    float4v __attribute__((ext_vector_type(4)));

__device__ __forceinline__ float fast_exp2(float x) {
#if defined(__has_builtin)
#if __has_builtin(__builtin_amdgcn_exp2f)
    return __builtin_amdgcn_exp2f(x);   // raw v_exp_f32
#else
    return exp2f(x);
#endif
#else
    return exp2f(x);
#endif
}

// ---------------------------------------------------------------------------
// Kernel 1: per-gaussian coefficient precompute in MFMA B-operand fragment
// layout (bfrag[tile*64 + lane] = half8), plus d_out zeroing.
// ---------------------------------------------------------------------------
__global__ __launch_bounds__(256) void precompute_bfrag(
    const float* __restrict__ pos, const float* __restrict__ scl,
    const float* __restrict__ rot, const float* __restrict__ inten,
    half8* __restrict__ bfrag, float4* __restrict__ out_zero)
{
    int n = blockIdx.x * 256 + threadIdx.x;
    if (n >= N_GAUSS) return;

    // zero d_out: 65536 floats = 16384 float4 across 4096 threads
    {
        float4 z = make_float4(0.f, 0.f, 0.f, 0.f);
        out_zero[n]         = z;
        out_zero[n + 4096]  = z;
        out_zero[n + 8192]  = z;
        out_zero[n + 12288] = z;
    }

    float qw = rot[4*n+0], qx = rot[4*n+1], qy = rot[4*n+2], qz = rot[4*n+3];
    float nrm = sqrtf(qw*qw + qx*qx + qy*qy + qz*qz) + 1e-8f;
    float ir = 1.0f / nrm;
    qw *= ir; qx *= ir; qy *= ir; qz *= ir;

    float r00 = 1.f - 2.f*(qy*qy + qz*qz);
    float r01 = 2.f*(qx*qy - qz*qw);
    float r02 = 2.f*(qx*qz + qy*qw);
    float r10 = 2.f*(qx*qy + qz*qw);
    float r11 = 1.f - 2.f*(qx*qx + qz*qz);
    float r12 = 2.f*(qy*qz - qx*qw);
    float r20 = 2.f*(qx*qz - qy*qw);
    float r21 = 2.f*(qy*qz + qx*qw);
    float r22 = 1.f - 2.f*(qx*qx + qy*qy);

    float s0 = fabsf(scl[3*n+0]) + 1e-6f;
    float s1 = fabsf(scl[3*n+1]) + 1e-6f;
    float s2 = fabsf(scl[3*n+2]) + 1e-6f;
    float w0 = 1.f/(s0*s0), w1 = 1.f/(s1*s1), w2 = 1.f/(s2*s2);

    float a00 = r00*r00*w0 + r01*r01*w1 + r02*r02*w2;
    float a01 = r00*r10*w0 + r01*r11*w1 + r02*r12*w2;
    float a02 = r00*r20*w0 + r01*r21*w1 + r02*r22*w2;
    float a11 = r10*r10*w0 + r11*r11*w1 + r12*r12*w2;
    float a12 = r10*r20*w0 + r11*r21*w1 + r12*r22*w2;
    float a22 = r20*r20*w0 + r21*r21*w1 + r22*r22*w2;

    float p0 = pos[3*n+0], p1 = pos[3*n+1], p2 = pos[3*n+2];
    float b0 = a00*p0 + a01*p1 + a02*p2;
    float b1 = a01*p0 + a11*p1 + a12*p2;
    float b2 = a02*p0 + a12*p1 + a22*p2;
    float c  = b0*p0 + b1*p1 + b2*p2;

    float I = fmaxf(inten[n], 1e-30f);   // I=0 -> t very negative -> exp2 -> 0

    float C[10];
    C[0] = KNEG * a00;       C[1] = KNEG * a11;       C[2] = KNEG * a22;
    C[3] = 2.f*KNEG * a01;   C[4] = 2.f*KNEG * a02;   C[5] = 2.f*KNEG * a12;
    C[6] = -2.f*KNEG * b0;   C[7] = -2.f*KNEG * b1;   C[8] = -2.f*KNEG * b2;
    C[9] = KNEG * c + log2f(I);

    _Float16 chi[10], clo[10];
#pragma unroll
    for (int j = 0; j < 10; ++j) {
        chi[j] = (_Float16)C[j];
        clo[j] = (_Float16)(C[j] - (float)chi[j]);
    }

    const int tile = n >> 4, nl = n & 15;
#pragma unroll
    for (int q = 0; q < 4; ++q) {
        half8 v;
#pragma unroll
        for (int j = 0; j < 8; ++j) {
            const int k = q*8 + j;
            _Float16 h = (_Float16)0.f;
            if (k < 30) {
                const int jm = k / 3, s = k % 3;
                h = (s == 2) ? clo[jm] : chi[jm];
            }
            v[j] = h;
        }
        bfrag[tile*64 + q*16 + nl] = v;
    }
}

// ---------------------------------------------------------------------------
// A-frag builder: all named scalars + first-class vectors (SROA-proof).
// k-slot layout: k=3j -> phi_j, 3j+1 -> plo_j, 3j+2 -> phi_j; k=30,31 -> 0.
// quad q holds k = q*8 .. q*8+7.
// ---------------------------------------------------------------------------
__device__ __forceinline__ half8 build_afrag(float x, float y, float z, int q) {
    const float P0 = x*x, P1 = y*y, P2 = z*z;
    const float P3 = x*y, P4 = x*z, P5 = y*z;

    _Float16 h0 = (_Float16)P0, l0 = (_Float16)(P0 - (float)h0);
    _Float16 h1 = (_Float16)P1, l1 = (_Float16)(P1 - (float)h1);
    _Float16 h2 = (_Float16)P2, l2 = (_Float16)(P2 - (float)h2);
    _Float16 h3 = (_Float16)P3, l3 = (_Float16)(P3 - (float)h3);
    _Float16 h4 = (_Float16)P4, l4 = (_Float16)(P4 - (float)h4);
    _Float16 h5 = (_Float16)P5, l5 = (_Float16)(P5 - (float)h5);
    _Float16 h6 = (_Float16)x,  l6 = (_Float16)(x - (float)h6);
    _Float16 h7 = (_Float16)y,  l7 = (_Float16)(y - (float)h7);
    _Float16 h8 = (_Float16)z,  l8 = (_Float16)(z - (float)h8);
    const _Float16 one = (_Float16)1.f, zer = (_Float16)0.f;

    // k:       0   1   2   3   4   5   6   7
    half8 c0 = {h0, l0, h0, h1, l1, h1, h2, l2};
    // k:       8   9  10  11  12  13  14  15
    half8 c1 = {h2, h3, l3, h3, h4, l4, h4, h5};
    // k:      16  17  18  19  20  21  22  23
    half8 c2 = {l5, h5, h6, l6, h6, h7, l7, h7};
    // k:      24  25  26  27  28  29  30  31
    half8 c3 = {h8, l8, h8, one, zer, one, zer, zer};

    return (q == 0) ? c0 : (q == 1) ? c1 : (q == 2) ? c2 : c3;
}

// ---------------------------------------------------------------------------
// Kernel 2: main evaluation. grid(256, 4) x 256 threads (4 waves/block).
// Each wave owns FOUR 16-point tiles (af0..af3 named half8). blockIdx.y
// splits 256 gaussian tiles into 4 chunks of 64 (4 double-buffered LDS
// rounds of 16 tiles, 32 KiB). atomicAdd partials (4 per output).
// ---------------------------------------------------------------------------
#define PT_SLABS  256
#define G_SPLIT   4
#define G_TILES   (256 / G_SPLIT)   // 64
#define RT        16
#define ROUNDS    (G_TILES / RT)    // 4

__global__ __launch_bounds__(256, 4) void gauss_eval(
    const float* __restrict__ pts,
    const half8* __restrict__ bfrag,
    float* __restrict__ out)
{
    __shared__ half8 lds[2 * RT * 64];   // 32 KiB

    const int tid  = threadIdx.x;
    const int lane = tid & 63;
    const int wv   = tid >> 6;
    const int ml   = lane & 15;          // A m-index / B n-index / D col
    const int q    = lane >> 4;          // k-group / D row-group

    const int base = blockIdx.x * 256 + wv * 64;   // first of this wave's 64 pts

    const int p0i = base + ml, p1i = base + 16 + ml;
    const int p2i = base + 32 + ml, p3i = base + 48 + ml;
    half8 af0 = build_afrag(pts[3*p0i], pts[3*p0i+1], pts[3*p0i+2], q);
    half8 af1 = build_afrag(pts[3*p1i], pts[3*p1i+1], pts[3*p1i+2], q);
    half8 af2 = build_afrag(pts[3*p2i], pts[3*p2i+1], pts[3*p2i+2], q);
    half8 af3 = build_afrag(pts[3*p3i], pts[3*p3i+1], pts[3*p3i+2], q);

    float a00 = 0.f, a01 = 0.f, a02 = 0.f, a03 = 0.f;
    float a10 = 0.f, a11 = 0.f, a12 = 0.f, a13 = 0.f;
    float a20 = 0.f, a21 = 0.f, a22 = 0.f, a23 = 0.f;
    float a30 = 0.f, a31 = 0.f, a32 = 0.f, a33 = 0.f;
    const float4v zero4 = {0.f, 0.f, 0.f, 0.f};

    const int gtile0 = blockIdx.y * G_TILES;

    // stage round 0 (each wave: 4 tiles, 16 B/lane coalesced)
    {
        const half8* src = bfrag + (gtile0 + wv*4) * 64;
        half8* dst = lds + (wv*4) * 64;
#pragma unroll
        for (int i = 0; i < 4; ++i) dst[i*64 + lane] = src[i*64 + lane];
    }
    __syncthreads();

    for (int r = 0; r < ROUNDS; ++r) {
        const half8* cur = lds + (r & 1) * (RT*64);
        half8* nxt       = lds + ((r + 1) & 1) * (RT*64);

        if (r < ROUNDS - 1) {
            const half8* src = bfrag + (gtile0 + (r+1)*RT + wv*4) * 64;
            half8* dst = nxt + (wv*4) * 64;
#pragma unroll
            for (int i = 0; i < 4; ++i) dst[i*64 + lane] = src[i*64 + lane];
        }

#pragma unroll
        for (int i = 0; i < RT; ++i) {
            half8 b = cur[i*64 + lane];
            float4v d0 = __builtin_amdgcn_mfma_f32_16x16x32_f16(af0, b, zero4, 0, 0, 0);
            float4v d1 = __builtin_amdgcn_mfma_f32_16x16x32_f16(af1, b, zero4, 0, 0, 0);
            float4v d2 = __builtin_amdgcn_mfma_f32_16x16x32_f16(af2, b, zero4, 0, 0, 0);
            float4v d3 = __builtin_amdgcn_mfma_f32_16x16x32_f16(af3, b, zero4, 0, 0, 0);
            a00 += fast_exp2(d0[0]); a01 += fast_exp2(d0[1]);
            a02 += fast_exp2(d0[2]); a03 += fast_exp2(d0[3]);
            a10 += fast_exp2(d1[0]); a11 += fast_exp2(d1[1]);
            a12 += fast_exp2(d1[2]); a13 += fast_exp2(d1[3]);
            a20 += fast_exp2(d2[0]); a21 += fast_exp2(d2[1]);
            a22 += fast_exp2(d2[2]); a23 += fast_exp2(d2[3]);
            a30 += fast_exp2(d3[0]); a31 += fast_exp2(d3[1]);
            a32 += fast_exp2(d3[2]); a33 += fast_exp2(d3[3]);
        }
        __syncthreads();
    }

    // reduce over the 16 gaussian lanes within each quad
#pragma unroll
    for (int m = 1; m <= 8; m <<= 1) {
        a00 += __shfl_xor(a00, m); a01 += __shfl_xor(a01, m);
        a02 += __shfl_xor(a02, m); a03 += __shfl_xor(a03, m);
        a10 += __shfl_xor(a10, m); a11 += __shfl_xor(a11, m);
        a12 += __shfl_xor(a12, m); a13 += __shfl_xor(a13, m);
        a20 += __shfl_xor(a20, m); a21 += __shfl_xor(a21, m);
        a22 += __shfl_xor(a22, m); a23 += __shfl_xor(a23, m);
        a30 += __shfl_xor(a30, m); a31 += __shfl_xor(a31, m);
        a32 += __shfl_xor(a32, m); a33 += __shfl_xor(a33, m);
    }

    // lane ml==0 of quad q holds sums for points base + f*16 + q*4 + r
    if (ml == 0) {
        const int o = base + q*4;
        atomicAdd(&out[o + 0],      a00);
        atomicAdd(&out[o + 1],      a01);
        atomicAdd(&out[o + 2],      a02);
        atomicAdd(&out[o + 3],      a03);
        atomicAdd(&out[o + 16],     a10);
        atomicAdd(&out[o + 17],     a11);
        atomicAdd(&out[o + 18],     a12);
        atomicAdd(&out[o + 19],     a13);
        atomicAdd(&out[o + 32],     a20);
        atomicAdd(&out[o + 33],     a21);
        atomicAdd(&out[o + 34],     a22);
        atomicAdd(&out[o + 35],     a23);
        atomicAdd(&out[o + 48],     a30);
        atomicAdd(&out[o + 49],     a31);
        atomicAdd(&out[o + 50],     a32);
        atomicAdd(&out[o + 51],     a33);
    }
}

extern "C" void kernel_launch(void* const* d_in, const int* in_sizes, int n_in,
                              void* d_out, int out_size, void* d_ws, size_t ws_size,
                              hipStream_t stream) {
    const float* sample_points = (const float*)d_in[0];
    const float* positions     = (const float*)d_in[1];
    const float* scales        = (const float*)d_in[2];
    const float* rotations     = (const float*)d_in[3];
    const float* intensities   = (const float*)d_in[4];

    half8* bfrag = (half8*)d_ws;   // 256 KiB

    precompute_bfrag<<<N_GAUSS / 256, 256, 0, stream>>>(
        positions, scales, rotations, intensities, bfrag, (float4*)d_out);

    gauss_eval<<<dim3(PT_SLABS, G_SPLIT), 256, 0, stream>>>(
        sample_points, bfrag, (float*)d_out);
}

// Round 7
// 100.354 us; speedup vs baseline: 1.9771x; 1.7003x over previous
//
#include <hip/hip_runtime.h>

// Gaussian mixture field evaluation via MFMA:
//   out[m] = sum_n exp2( K*q[m,n] + log2(I_n) ),  K = -0.5*log2(e)
// q expressed as dot(P[m][0..9], C[n][0..9]) with split-f16 (hi/lo) operands:
// products hi*hi + lo*hi + hi*lo -> 30 K-slots -> one mfma_f32_16x16x32_f16
// per 16x16 q-tile.
//
// Round 7: TWO point-tiles per wave (round 5/6's four blew past the
// allocator's 64-VGPR target -> ~1.2 KB/thread scratch spill -> 460 MB HBM
// round-trip, the entire 112 us). Peak pressure now ~40 VGPRs: af0/af1 (8)
// + b (4) + d0/d1 (8) + 8 accumulators + addressing. Plain
// __launch_bounds__(256) (no min-waves hint that pins the allocator).
//
// Verified gfx950 layouts (learn_hip m89/m91):
//   A-frag: lane holds A[m=lane&15][k=(lane>>4)*8+j], j=0..7
//   B-frag: lane holds B[k=(lane>>4)*8+j][n=lane&15]
//   D:      lane holds D[row=(lane>>4)*4+r][col=lane&15], r=0..3

#define M_POINTS 65536
#define N_GAUSS  4096
#define KNEG     (-0.72134752044448170f)   // -0.5 * log2(e)

typedef _Float16 half8   __attribute__((ext_vector_type(8)));
typedef float    float4v __attribute__((ext_vector_type(4)));

__device__ __forceinline__ float fast_exp2(float x) {
#if defined(__has_builtin)
#if __has_builtin(__builtin_amdgcn_exp2f)
    return __builtin_amdgcn_exp2f(x);   // raw v_exp_f32
#else
    return exp2f(x);
#endif
#else
    return exp2f(x);
#endif
}

// ---------------------------------------------------------------------------
// Kernel 1: per-gaussian coefficient precompute in MFMA B-operand fragment
// layout (bfrag[tile*64 + lane] = half8), plus d_out zeroing.
// ---------------------------------------------------------------------------
__global__ __launch_bounds__(256) void precompute_bfrag(
    const float* __restrict__ pos, const float* __restrict__ scl,
    const float* __restrict__ rot, const float* __restrict__ inten,
    half8* __restrict__ bfrag, float4* __restrict__ out_zero)
{
    int n = blockIdx.x * 256 + threadIdx.x;
    if (n >= N_GAUSS) return;

    // zero d_out: 65536 floats = 16384 float4 across 4096 threads
    {
        float4 z = make_float4(0.f, 0.f, 0.f, 0.f);
        out_zero[n]         = z;
        out_zero[n + 4096]  = z;
        out_zero[n + 8192]  = z;
        out_zero[n + 12288] = z;
    }

    float qw = rot[4*n+0], qx = rot[4*n+1], qy = rot[4*n+2], qz = rot[4*n+3];
    float nrm = sqrtf(qw*qw + qx*qx + qy*qy + qz*qz) + 1e-8f;
    float ir = 1.0f / nrm;
    qw *= ir; qx *= ir; qy *= ir; qz *= ir;

    float r00 = 1.f - 2.f*(qy*qy + qz*qz);
    float r01 = 2.f*(qx*qy - qz*qw);
    float r02 = 2.f*(qx*qz + qy*qw);
    float r10 = 2.f*(qx*qy + qz*qw);
    float r11 = 1.f - 2.f*(qx*qx + qz*qz);
    float r12 = 2.f*(qy*qz - qx*qw);
    float r20 = 2.f*(qx*qz - qy*qw);
    float r21 = 2.f*(qy*qz + qx*qw);
    float r22 = 1.f - 2.f*(qx*qx + qy*qy);

    float s0 = fabsf(scl[3*n+0]) + 1e-6f;
    float s1 = fabsf(scl[3*n+1]) + 1e-6f;
    float s2 = fabsf(scl[3*n+2]) + 1e-6f;
    float w0 = 1.f/(s0*s0), w1 = 1.f/(s1*s1), w2 = 1.f/(s2*s2);

    float a00 = r00*r00*w0 + r01*r01*w1 + r02*r02*w2;
    float a01 = r00*r10*w0 + r01*r11*w1 + r02*r12*w2;
    float a02 = r00*r20*w0 + r01*r21*w1 + r02*r22*w2;
    float a11 = r10*r10*w0 + r11*r11*w1 + r12*r12*w2;
    float a12 = r10*r20*w0 + r11*r21*w1 + r12*r22*w2;
    float a22 = r20*r20*w0 + r21*r21*w1 + r22*r22*w2;

    float p0 = pos[3*n+0], p1 = pos[3*n+1], p2 = pos[3*n+2];
    float b0 = a00*p0 + a01*p1 + a02*p2;
    float b1 = a01*p0 + a11*p1 + a12*p2;
    float b2 = a02*p0 + a12*p1 + a22*p2;
    float c  = b0*p0 + b1*p1 + b2*p2;

    float I = fmaxf(inten[n], 1e-30f);   // I=0 -> t very negative -> exp2 -> 0

    float C[10];
    C[0] = KNEG * a00;       C[1] = KNEG * a11;       C[2] = KNEG * a22;
    C[3] = 2.f*KNEG * a01;   C[4] = 2.f*KNEG * a02;   C[5] = 2.f*KNEG * a12;
    C[6] = -2.f*KNEG * b0;   C[7] = -2.f*KNEG * b1;   C[8] = -2.f*KNEG * b2;
    C[9] = KNEG * c + log2f(I);

    _Float16 chi[10], clo[10];
#pragma unroll
    for (int j = 0; j < 10; ++j) {
        chi[j] = (_Float16)C[j];
        clo[j] = (_Float16)(C[j] - (float)chi[j]);
    }

    const int tile = n >> 4, nl = n & 15;
#pragma unroll
    for (int q = 0; q < 4; ++q) {
        half8 v;
#pragma unroll
        for (int j = 0; j < 8; ++j) {
            const int k = q*8 + j;
            _Float16 h = (_Float16)0.f;
            if (k < 30) {
                const int jm = k / 3, s = k % 3;
                h = (s == 2) ? clo[jm] : chi[jm];
            }
            v[j] = h;
        }
        bfrag[tile*64 + q*16 + nl] = v;
    }
}

// ---------------------------------------------------------------------------
// A-frag builder: named scalars + first-class vectors only.
// k-slot layout: k=3j -> phi_j, 3j+1 -> plo_j, 3j+2 -> phi_j; k=30,31 -> 0.
// quad q holds k = q*8 .. q*8+7.
// ---------------------------------------------------------------------------
__device__ __forceinline__ half8 build_afrag(float x, float y, float z, int q) {
    const float P0 = x*x, P1 = y*y, P2 = z*z;
    const float P3 = x*y, P4 = x*z, P5 = y*z;

    _Float16 h0 = (_Float16)P0, l0 = (_Float16)(P0 - (float)h0);
    _Float16 h1 = (_Float16)P1, l1 = (_Float16)(P1 - (float)h1);
    _Float16 h2 = (_Float16)P2, l2 = (_Float16)(P2 - (float)h2);
    _Float16 h3 = (_Float16)P3, l3 = (_Float16)(P3 - (float)h3);
    _Float16 h4 = (_Float16)P4, l4 = (_Float16)(P4 - (float)h4);
    _Float16 h5 = (_Float16)P5, l5 = (_Float16)(P5 - (float)h5);
    _Float16 h6 = (_Float16)x,  l6 = (_Float16)(x - (float)h6);
    _Float16 h7 = (_Float16)y,  l7 = (_Float16)(y - (float)h7);
    _Float16 h8 = (_Float16)z,  l8 = (_Float16)(z - (float)h8);
    const _Float16 one = (_Float16)1.f, zer = (_Float16)0.f;

    // k:       0   1   2   3   4   5   6   7
    half8 c0 = {h0, l0, h0, h1, l1, h1, h2, l2};
    // k:       8   9  10  11  12  13  14  15
    half8 c1 = {h2, h3, l3, h3, h4, l4, h4, h5};
    // k:      16  17  18  19  20  21  22  23
    half8 c2 = {l5, h5, h6, l6, h6, h7, l7, h7};
    // k:      24  25  26  27  28  29  30  31
    half8 c3 = {h8, l8, h8, one, zer, one, zer, zer};

    return (q == 0) ? c0 : (q == 1) ? c1 : (q == 2) ? c2 : c3;
}

// ---------------------------------------------------------------------------
// Kernel 2: main evaluation. grid(512, 2) x 256 threads (4 waves/block).
// Each wave owns TWO 16-point tiles (af0, af1). blockIdx.y splits 256
// gaussian tiles into 2 chunks of 128 (8 double-buffered LDS rounds of 16
// tiles, 32 KiB). Each ds_read_b128 of a B-frag feeds 2 MFMAs / 8 exp2s.
// atomicAdd partials (2 per output element).
// ---------------------------------------------------------------------------
#define PT_SLABS  512               // 65536 / 128 points per block
#define G_SPLIT   2
#define G_TILES   (256 / G_SPLIT)   // 128
#define RT        16
#define ROUNDS    (G_TILES / RT)    // 8

__global__ __launch_bounds__(256) void gauss_eval(
    const float* __restrict__ pts,
    const half8* __restrict__ bfrag,
    float* __restrict__ out)
{
    __shared__ half8 lds[2 * RT * 64];   // 32 KiB

    const int tid  = threadIdx.x;
    const int lane = tid & 63;
    const int wv   = tid >> 6;
    const int ml   = lane & 15;          // A m-index / B n-index / D col
    const int q    = lane >> 4;          // k-group / D row-group

    const int base = blockIdx.x * 128 + wv * 32;   // first of this wave's 32 pts

    const int p0i = base + ml, p1i = base + 16 + ml;
    half8 af0 = build_afrag(pts[3*p0i], pts[3*p0i+1], pts[3*p0i+2], q);
    half8 af1 = build_afrag(pts[3*p1i], pts[3*p1i+1], pts[3*p1i+2], q);

    float a00 = 0.f, a01 = 0.f, a02 = 0.f, a03 = 0.f;
    float a10 = 0.f, a11 = 0.f, a12 = 0.f, a13 = 0.f;
    const float4v zero4 = {0.f, 0.f, 0.f, 0.f};

    const int gtile0 = blockIdx.y * G_TILES;

    // stage round 0 (each wave: 4 tiles, 16 B/lane coalesced)
    {
        const half8* src = bfrag + (gtile0 + wv*4) * 64;
        half8* dst = lds + (wv*4) * 64;
#pragma unroll
        for (int i = 0; i < 4; ++i) dst[i*64 + lane] = src[i*64 + lane];
    }
    __syncthreads();

    for (int r = 0; r < ROUNDS; ++r) {
        const half8* cur = lds + (r & 1) * (RT*64);
        half8* nxt       = lds + ((r + 1) & 1) * (RT*64);

        if (r < ROUNDS - 1) {
            const half8* src = bfrag + (gtile0 + (r+1)*RT + wv*4) * 64;
            half8* dst = nxt + (wv*4) * 64;
#pragma unroll
            for (int i = 0; i < 4; ++i) dst[i*64 + lane] = src[i*64 + lane];
        }

#pragma unroll
        for (int i = 0; i < RT; ++i) {
            half8 b = cur[i*64 + lane];
            float4v d0 = __builtin_amdgcn_mfma_f32_16x16x32_f16(af0, b, zero4, 0, 0, 0);
            float4v d1 = __builtin_amdgcn_mfma_f32_16x16x32_f16(af1, b, zero4, 0, 0, 0);
            a00 += fast_exp2(d0[0]); a01 += fast_exp2(d0[1]);
            a02 += fast_exp2(d0[2]); a03 += fast_exp2(d0[3]);
            a10 += fast_exp2(d1[0]); a11 += fast_exp2(d1[1]);
            a12 += fast_exp2(d1[2]); a13 += fast_exp2(d1[3]);
        }
        __syncthreads();
    }

    // reduce over the 16 gaussian lanes within each quad
#pragma unroll
    for (int m = 1; m <= 8; m <<= 1) {
        a00 += __shfl_xor(a00, m); a01 += __shfl_xor(a01, m);
        a02 += __shfl_xor(a02, m); a03 += __shfl_xor(a03, m);
        a10 += __shfl_xor(a10, m); a11 += __shfl_xor(a11, m);
        a12 += __shfl_xor(a12, m); a13 += __shfl_xor(a13, m);
    }

    // lane ml==0 of quad q holds sums for points base + f*16 + q*4 + r
    if (ml == 0) {
        const int o = base + q*4;
        atomicAdd(&out[o + 0],  a00);
        atomicAdd(&out[o + 1],  a01);
        atomicAdd(&out[o + 2],  a02);
        atomicAdd(&out[o + 3],  a03);
        atomicAdd(&out[o + 16], a10);
        atomicAdd(&out[o + 17], a11);
        atomicAdd(&out[o + 18], a12);
        atomicAdd(&out[o + 19], a13);
    }
}

extern "C" void kernel_launch(void* const* d_in, const int* in_sizes, int n_in,
                              void* d_out, int out_size, void* d_ws, size_t ws_size,
                              hipStream_t stream) {
    const float* sample_points = (const float*)d_in[0];
    const float* positions     = (const float*)d_in[1];
    const float* scales        = (const float*)d_in[2];
    const float* rotations     = (const float*)d_in[3];
    const float* intensities   = (const float*)d_in[4];

    half8* bfrag = (half8*)d_ws;   // 256 KiB

    precompute_bfrag<<<N_GAUSS / 256, 256, 0, stream>>>(
        positions, scales, rotations, intensities, bfrag, (float4*)d_out);

    gauss_eval<<<dim3(PT_SLABS, G_SPLIT), 256, 0, stream>>>(
        sample_points, bfrag, (float*)d_out);
}

// Round 8
// 96.728 us; speedup vs baseline: 2.0512x; 1.0375x over previous
//
#include <hip/hip_runtime.h>

// Gaussian mixture field evaluation via MFMA:
//   out[m] = sum_n exp2( K*q[m,n] + log2(I_n) ),  K = -0.5*log2(e)
// q expressed as dot(P[m][0..9], C[n][0..9]) with split-f16 (hi/lo) operands:
// products hi*hi + lo*hi + hi*lo -> 30 K-slots -> one mfma_f32_16x16x32_f16
// per 16x16 q-tile. Two point-tiles per wave (keeps VGPR<=64 -> 8 waves/SIMD
// legal; four tiles spilled to scratch in rounds 5/6).
//
// Round 8: occupancy 4->8 waves/SIMD (LDS 32->16 KiB via RT=8, grid 2048
// blocks via G_SPLIT=4) + v_pk_add_f32 accumulation (float2 accs). The exp
// trans-pipe time (13.6 us total) is the structural floor; everything else
// must hide behind it.
//
// Verified gfx950 layouts (learn_hip m89/m91):
//   A-frag: lane holds A[m=lane&15][k=(lane>>4)*8+j], j=0..7
//   B-frag: lane holds B[k=(lane>>4)*8+j][n=lane&15]
//   D:      lane holds D[row=(lane>>4)*4+r][col=lane&15], r=0..3

#define M_POINTS 65536
#define N_GAUSS  4096
#define KNEG     (-0.72134752044448170f)   // -0.5 * log2(e)

typedef _Float16 half8   __attribute__((ext_vector_type(8)));
typedef float    float4v __attribute__((ext_vector_type(4)));
typedef float    v2f     __attribute__((ext_vector_type(2)));

__device__ __forceinline__ float fast_exp2(float x) {
#if defined(__has_builtin)
#if __has_builtin(__builtin_amdgcn_exp2f)
    return __builtin_amdgcn_exp2f(x);   // raw v_exp_f32
#else
    return exp2f(x);
#endif
#else
    return exp2f(x);
#endif
}

// ---------------------------------------------------------------------------
// Kernel 1: per-gaussian coefficient precompute in MFMA B-operand fragment
// layout (bfrag[tile*64 + lane] = half8), plus d_out zeroing.
// ---------------------------------------------------------------------------
__global__ __launch_bounds__(256) void precompute_bfrag(
    const float* __restrict__ pos, const float* __restrict__ scl,
    const float* __restrict__ rot, const float* __restrict__ inten,
    half8* __restrict__ bfrag, float4* __restrict__ out_zero)
{
    int n = blockIdx.x * 256 + threadIdx.x;
    if (n >= N_GAUSS) return;

    // zero d_out: 65536 floats = 16384 float4 across 4096 threads
    {
        float4 z = make_float4(0.f, 0.f, 0.f, 0.f);
        out_zero[n]         = z;
        out_zero[n + 4096]  = z;
        out_zero[n + 8192]  = z;
        out_zero[n + 12288] = z;
    }

    float qw = rot[4*n+0], qx = rot[4*n+1], qy = rot[4*n+2], qz = rot[4*n+3];
    float nrm = sqrtf(qw*qw + qx*qx + qy*qy + qz*qz) + 1e-8f;
    float ir = 1.0f / nrm;
    qw *= ir; qx *= ir; qy *= ir; qz *= ir;

    float r00 = 1.f - 2.f*(qy*qy + qz*qz);
    float r01 = 2.f*(qx*qy - qz*qw);
    float r02 = 2.f*(qx*qz + qy*qw);
    float r10 = 2.f*(qx*qy + qz*qw);
    float r11 = 1.f - 2.f*(qx*qx + qz*qz);
    float r12 = 2.f*(qy*qz - qx*qw);
    float r20 = 2.f*(qx*qz - qy*qw);
    float r21 = 2.f*(qy*qz + qx*qw);
    float r22 = 1.f - 2.f*(qx*qx + qy*qy);

    float s0 = fabsf(scl[3*n+0]) + 1e-6f;
    float s1 = fabsf(scl[3*n+1]) + 1e-6f;
    float s2 = fabsf(scl[3*n+2]) + 1e-6f;
    float w0 = 1.f/(s0*s0), w1 = 1.f/(s1*s1), w2 = 1.f/(s2*s2);

    float a00 = r00*r00*w0 + r01*r01*w1 + r02*r02*w2;
    float a01 = r00*r10*w0 + r01*r11*w1 + r02*r12*w2;
    float a02 = r00*r20*w0 + r01*r21*w1 + r02*r22*w2;
    float a11 = r10*r10*w0 + r11*r11*w1 + r12*r12*w2;
    float a12 = r10*r20*w0 + r11*r21*w1 + r12*r22*w2;
    float a22 = r20*r20*w0 + r21*r21*w1 + r22*r22*w2;

    float p0 = pos[3*n+0], p1 = pos[3*n+1], p2 = pos[3*n+2];
    float b0 = a00*p0 + a01*p1 + a02*p2;
    float b1 = a01*p0 + a11*p1 + a12*p2;
    float b2 = a02*p0 + a12*p1 + a22*p2;
    float c  = b0*p0 + b1*p1 + b2*p2;

    float I = fmaxf(inten[n], 1e-30f);   // I=0 -> t very negative -> exp2 -> 0

    float C[10];
    C[0] = KNEG * a00;       C[1] = KNEG * a11;       C[2] = KNEG * a22;
    C[3] = 2.f*KNEG * a01;   C[4] = 2.f*KNEG * a02;   C[5] = 2.f*KNEG * a12;
    C[6] = -2.f*KNEG * b0;   C[7] = -2.f*KNEG * b1;   C[8] = -2.f*KNEG * b2;
    C[9] = KNEG * c + log2f(I);

    _Float16 chi[10], clo[10];
#pragma unroll
    for (int j = 0; j < 10; ++j) {
        chi[j] = (_Float16)C[j];
        clo[j] = (_Float16)(C[j] - (float)chi[j]);
    }

    const int tile = n >> 4, nl = n & 15;
#pragma unroll
    for (int q = 0; q < 4; ++q) {
        half8 v;
#pragma unroll
        for (int j = 0; j < 8; ++j) {
            const int k = q*8 + j;
            _Float16 h = (_Float16)0.f;
            if (k < 30) {
                const int jm = k / 3, s = k % 3;
                h = (s == 2) ? clo[jm] : chi[jm];
            }
            v[j] = h;
        }
        bfrag[tile*64 + q*16 + nl] = v;
    }
}

// ---------------------------------------------------------------------------
// A-frag builder: named scalars + first-class vectors only (SROA-proof).
// k-slot layout: k=3j -> phi_j, 3j+1 -> plo_j, 3j+2 -> phi_j; k=30,31 -> 0.
// quad q holds k = q*8 .. q*8+7.
// ---------------------------------------------------------------------------
__device__ __forceinline__ half8 build_afrag(float x, float y, float z, int q) {
    const float P0 = x*x, P1 = y*y, P2 = z*z;
    const float P3 = x*y, P4 = x*z, P5 = y*z;

    _Float16 h0 = (_Float16)P0, l0 = (_Float16)(P0 - (float)h0);
    _Float16 h1 = (_Float16)P1, l1 = (_Float16)(P1 - (float)h1);
    _Float16 h2 = (_Float16)P2, l2 = (_Float16)(P2 - (float)h2);
    _Float16 h3 = (_Float16)P3, l3 = (_Float16)(P3 - (float)h3);
    _Float16 h4 = (_Float16)P4, l4 = (_Float16)(P4 - (float)h4);
    _Float16 h5 = (_Float16)P5, l5 = (_Float16)(P5 - (float)h5);
    _Float16 h6 = (_Float16)x,  l6 = (_Float16)(x - (float)h6);
    _Float16 h7 = (_Float16)y,  l7 = (_Float16)(y - (float)h7);
    _Float16 h8 = (_Float16)z,  l8 = (_Float16)(z - (float)h8);
    const _Float16 one = (_Float16)1.f, zer = (_Float16)0.f;

    // k:       0   1   2   3   4   5   6   7
    half8 c0 = {h0, l0, h0, h1, l1, h1, h2, l2};
    // k:       8   9  10  11  12  13  14  15
    half8 c1 = {h2, h3, l3, h3, h4, l4, h4, h5};
    // k:      16  17  18  19  20  21  22  23
    half8 c2 = {l5, h5, h6, l6, h6, h7, l7, h7};
    // k:      24  25  26  27  28  29  30  31
    half8 c3 = {h8, l8, h8, one, zer, one, zer, zer};

    return (q == 0) ? c0 : (q == 1) ? c1 : (q == 2) ? c2 : c3;
}

// ---------------------------------------------------------------------------
// Kernel 2: main evaluation. grid(512, 4) x 256 threads (4 waves/block,
// 8 blocks/CU -> 32 waves/CU, the cap). Each wave owns TWO 16-point tiles.
// blockIdx.y splits 256 gaussian tiles into 4 chunks of 64 (8 double-
// buffered LDS rounds of 8 tiles, 16 KiB). Each ds_read_b128 feeds 2 MFMAs
// / 8 exp2s; accumulation packed as float2 (v_pk_add_f32).
// atomicAdd partials (4 per output element).
// ---------------------------------------------------------------------------
#define PT_SLABS  512               // 65536 / 128 points per block
#define G_SPLIT   4
#define G_TILES   (256 / G_SPLIT)   // 64
#define RT        8
#define ROUNDS    (G_TILES / RT)    // 8

__global__ __launch_bounds__(256) void gauss_eval(
    const float* __restrict__ pts,
    const half8* __restrict__ bfrag,
    float* __restrict__ out)
{
    __shared__ half8 lds[2 * RT * 64];   // 16 KiB

    const int tid  = threadIdx.x;
    const int lane = tid & 63;
    const int wv   = tid >> 6;
    const int ml   = lane & 15;          // A m-index / B n-index / D col
    const int q    = lane >> 4;          // k-group / D row-group

    const int base = blockIdx.x * 128 + wv * 32;   // first of this wave's 32 pts

    const int p0i = base + ml, p1i = base + 16 + ml;
    half8 af0 = build_afrag(pts[3*p0i], pts[3*p0i+1], pts[3*p0i+2], q);
    half8 af1 = build_afrag(pts[3*p1i], pts[3*p1i+1], pts[3*p1i+2], q);

    v2f a0lo = {0.f, 0.f}, a0hi = {0.f, 0.f};   // point-tile 0: d[0],d[1] / d[2],d[3]
    v2f a1lo = {0.f, 0.f}, a1hi = {0.f, 0.f};   // point-tile 1
    const float4v zero4 = {0.f, 0.f, 0.f, 0.f};

    const int gtile0 = blockIdx.y * G_TILES;

    // stage round 0 (each wave: 2 tiles, 16 B/lane coalesced)
    {
        const half8* src = bfrag + (gtile0 + wv*2) * 64;
        half8* dst = lds + (wv*2) * 64;
#pragma unroll
        for (int i = 0; i < 2; ++i) dst[i*64 + lane] = src[i*64 + lane];
    }
    __syncthreads();

    for (int r = 0; r < ROUNDS; ++r) {
        const half8* cur = lds + (r & 1) * (RT*64);
        half8* nxt       = lds + ((r + 1) & 1) * (RT*64);

        if (r < ROUNDS - 1) {
            const half8* src = bfrag + (gtile0 + (r+1)*RT + wv*2) * 64;
            half8* dst = nxt + (wv*2) * 64;
#pragma unroll
            for (int i = 0; i < 2; ++i) dst[i*64 + lane] = src[i*64 + lane];
        }

#pragma unroll
        for (int i = 0; i < RT; ++i) {
            half8 b = cur[i*64 + lane];
            float4v d0 = __builtin_amdgcn_mfma_f32_16x16x32_f16(af0, b, zero4, 0, 0, 0);
            float4v d1 = __builtin_amdgcn_mfma_f32_16x16x32_f16(af1, b, zero4, 0, 0, 0);
            v2f e0lo = { fast_exp2(d0[0]), fast_exp2(d0[1]) };
            v2f e0hi = { fast_exp2(d0[2]), fast_exp2(d0[3]) };
            v2f e1lo = { fast_exp2(d1[0]), fast_exp2(d1[1]) };
            v2f e1hi = { fast_exp2(d1[2]), fast_exp2(d1[3]) };
            a0lo += e0lo;   // v_pk_add_f32
            a0hi += e0hi;
            a1lo += e1lo;
            a1hi += e1hi;
        }
        __syncthreads();
    }

    // reduce over the 16 gaussian lanes within each quad (pk adds too)
#pragma unroll
    for (int m = 1; m <= 8; m <<= 1) {
        v2f t0lo = { __shfl_xor(a0lo.x, m), __shfl_xor(a0lo.y, m) };
        v2f t0hi = { __shfl_xor(a0hi.x, m), __shfl_xor(a0hi.y, m) };
        v2f t1lo = { __shfl_xor(a1lo.x, m), __shfl_xor(a1lo.y, m) };
        v2f t1hi = { __shfl_xor(a1hi.x, m), __shfl_xor(a1hi.y, m) };
        a0lo += t0lo; a0hi += t0hi; a1lo += t1lo; a1hi += t1hi;
    }

    // lane ml==0 of quad q holds sums for points base + f*16 + q*4 + r
    if (ml == 0) {
        const int o = base + q*4;
        atomicAdd(&out[o + 0],  a0lo.x);
        atomicAdd(&out[o + 1],  a0lo.y);
        atomicAdd(&out[o + 2],  a0hi.x);
        atomicAdd(&out[o + 3],  a0hi.y);
        atomicAdd(&out[o + 16], a1lo.x);
        atomicAdd(&out[o + 17], a1lo.y);
        atomicAdd(&out[o + 18], a1hi.x);
        atomicAdd(&out[o + 19], a1hi.y);
    }
}

extern "C" void kernel_launch(void* const* d_in, const int* in_sizes, int n_in,
                              void* d_out, int out_size, void* d_ws, size_t ws_size,
                              hipStream_t stream) {
    const float* sample_points = (const float*)d_in[0];
    const float* positions     = (const float*)d_in[1];
    const float* scales        = (const float*)d_in[2];
    const float* rotations     = (const float*)d_in[3];
    const float* intensities   = (const float*)d_in[4];

    half8* bfrag = (half8*)d_ws;   // 256 KiB

    precompute_bfrag<<<N_GAUSS / 256, 256, 0, stream>>>(
        positions, scales, rotations, intensities, bfrag, (float4*)d_out);

    gauss_eval<<<dim3(PT_SLABS, G_SPLIT), 256, 0, stream>>>(
        sample_points, bfrag, (float*)d_out);
}